// Round 3
// baseline (93.730 us; speedup 1.0000x reference)
//
#include <hip/hip_runtime.h>

// ---------------------------------------------------------------------------
// Clifford algebra Cl(3,1,0) geometric product, DIM = 16 blades.
//   out[n][c] = sum_{i,j: i^j == c} sign(i,j) * a[n][i] * b[n][j]
// Compile-time Cayley sign table; fully unrolled 256-FMA body (signs fold
// into the FMA negate modifier). Memory-bound: 128 MiB read + 64 MiB write.
//
// R3: non-temporal output stores via native clang vector type (HIP float4 is
// a class and is rejected by __builtin_nontemporal_store). Output has zero
// reuse; keeping it out of L2/L3 lets BOTH inputs (128 MiB) stay
// Infinity-Cache-resident across graph replays, cutting HBM FETCH.
// 1 row/thread, 4096 blocks.
// ---------------------------------------------------------------------------

typedef float vfloat4 __attribute__((ext_vector_type(4)));

struct CayleyTab { signed char s[16][16]; };

constexpr CayleyTab build_tab() {
    CayleyTab t{};
    for (int i = 0; i < 16; ++i) {
        for (int j = 0; j < 16; ++j) {
            int sum = 0;
            // canonical reordering swap parity: sum_k popcount((i >> (k+1)) & j)
            for (int a = i >> 1; a; a >>= 1) {
                int m = a & j;
                while (m) { sum += (m & 1); m >>= 1; }
            }
            // metric: generator 3 (bit 3) squares to -1; bits 0..2 square to +1
            sum += ((i & j) >> 3) & 1;
            t.s[i][j] = (signed char)((sum & 1) ? -1 : 1);
        }
    }
    return t;
}

constexpr CayleyTab TAB = build_tab();

__device__ __forceinline__ float clip1000(float v) {
    return fminf(fmaxf(v, -1000.0f), 1000.0f);
}

__global__ __launch_bounds__(256) void clifford_gp_kernel(
        const float* __restrict__ a,
        const float* __restrict__ b,
        float* __restrict__ out,
        int nrows) {
    const int row = blockIdx.x * blockDim.x + threadIdx.x;
    if (row >= nrows) return;

    const vfloat4* a4 = reinterpret_cast<const vfloat4*>(a) + (size_t)row * 4;
    const vfloat4* b4 = reinterpret_cast<const vfloat4*>(b) + (size_t)row * 4;

    float av[16], bv[16];
    #pragma unroll
    for (int k = 0; k < 4; ++k) {
        const vfloat4 ta = a4[k];
        av[4 * k + 0] = ta.x; av[4 * k + 1] = ta.y;
        av[4 * k + 2] = ta.z; av[4 * k + 3] = ta.w;
        const vfloat4 tb = b4[k];
        bv[4 * k + 0] = tb.x; bv[4 * k + 1] = tb.y;
        bv[4 * k + 2] = tb.z; bv[4 * k + 3] = tb.w;
    }

    float acc[16];
    #pragma unroll
    for (int c = 0; c < 16; ++c) acc[c] = 0.0f;

    #pragma unroll
    for (int i = 0; i < 16; ++i) {
        #pragma unroll
        for (int j = 0; j < 16; ++j) {
            const int c = i ^ j;
            if (TAB.s[i][j] > 0) acc[c] = fmaf(av[i],  bv[j], acc[c]);
            else                 acc[c] = fmaf(av[i], -bv[j], acc[c]);
        }
    }

    vfloat4* o4 = reinterpret_cast<vfloat4*>(out) + (size_t)row * 4;
    #pragma unroll
    for (int k = 0; k < 4; ++k) {
        vfloat4 t;
        t.x = clip1000(acc[4 * k + 0]);
        t.y = clip1000(acc[4 * k + 1]);
        t.z = clip1000(acc[4 * k + 2]);
        t.w = clip1000(acc[4 * k + 3]);
        __builtin_nontemporal_store(t, o4 + k);
    }
}

extern "C" void kernel_launch(void* const* d_in, const int* in_sizes, int n_in,
                              void* d_out, int out_size, void* d_ws, size_t ws_size,
                              hipStream_t stream) {
    const float* a = (const float*)d_in[0];
    const float* b = (const float*)d_in[1];
    float* out = (float*)d_out;

    const int nrows = in_sizes[0] / 16;   // N = 1048576
    const int block = 256;
    const int blocks = (nrows + block - 1) / block;  // 4096: 1 row/thread

    clifford_gp_kernel<<<blocks, block, 0, stream>>>(a, b, out, nrows);
}

// Round 4
// 34.190 us; speedup vs baseline: 2.7415x; 2.7415x over previous
//
#include <hip/hip_runtime.h>

// ---------------------------------------------------------------------------
// Clifford algebra Cl(3,1,0) geometric product, DIM = 16 blades (f32).
//   out[n][c] = sum_{i,j: i^j == c} sign(i,j) * a[n][i] * b[n][j]
//
// R4: fully-coalesced global access + per-wave LDS redistribution.
//  - Every global load/store: lane l <-> base + l*16B (contiguous 1KB/wave
//    per instruction) instead of R1's 64B-strided pattern (25% per-instr
//    line utilization, measured 3.6 TB/s HBM).
//  - Redistribution g-order <-> row-order via LDS, row stride padded to
//    68 floats (272B). ds_*_b128 by 64 lanes is 8 LDS phases minimum (1KB
//    per instr / 128B per cycle); this layout puts exactly 8 lanes per
//    4-bank quad on BOTH access patterns -> at the throughput floor.
//  - LDS buffer is per-wave private -> no __syncthreads; a/b/out phases
//    reuse the same buffer, ordered by the compiler's lgkmcnt deps.
//  - Normal stores (R3 showed non-temporal = 2.7x HBM write amplification).
// ---------------------------------------------------------------------------

typedef float vfloat4 __attribute__((ext_vector_type(4)));

struct CayleyTab { signed char s[16][16]; };

constexpr CayleyTab build_tab() {
    CayleyTab t{};
    for (int i = 0; i < 16; ++i) {
        for (int j = 0; j < 16; ++j) {
            int sum = 0;
            // canonical reordering swap parity: sum_k popcount((i >> (k+1)) & j)
            for (int a = i >> 1; a; a >>= 1) {
                int m = a & j;
                while (m) { sum += (m & 1); m >>= 1; }
            }
            // metric: generator 3 (bit 3) squares to -1; bits 0..2 square to +1
            sum += ((i & j) >> 3) & 1;
            t.s[i][j] = (signed char)((sum & 1) ? -1 : 1);
        }
    }
    return t;
}

constexpr CayleyTab TAB = build_tab();

__device__ __forceinline__ float clip1000(float v) {
    return fminf(fmaxf(v, -1000.0f), 1000.0f);
}

#define ROW_STRIDE 68   // floats; 272B, breaks bank alignment, keeps 16B align

__global__ __launch_bounds__(128) void clifford_gp_kernel(
        const float* __restrict__ a,
        const float* __restrict__ b,
        float* __restrict__ out,
        int nrows) {
    // 2 waves/block, each wave owns 64 rows and a private padded LDS tile.
    __shared__ float lds[2][64 * ROW_STRIDE];   // 2 x 17408 B = 34816 B

    const int wid  = threadIdx.x >> 6;
    const int lane = threadIdx.x & 63;
    float* buf = lds[wid];

    const int R0 = blockIdx.x * 128 + wid * 64;       // wave's first row
    if (R0 >= nrows) return;
    const size_t gbase = (size_t)R0 * 16;             // float offset of tile

    // g-order <-> padded offsets: quarter g = 64k + lane lives at
    //   row (16k + (lane>>2)), slot (lane&3)
    const int wrow = lane >> 2;
    const int wq   = (lane & 3) * 4;

    // ---- coalesced global loads: lane l takes 16B at tile_byte + k*1KB + l*16
    vfloat4 pa[4], pb[4];
    #pragma unroll
    for (int k = 0; k < 4; ++k) {
        pa[k] = *reinterpret_cast<const vfloat4*>(a + gbase + (size_t)(k * 64 + lane) * 4);
        pb[k] = *reinterpret_cast<const vfloat4*>(b + gbase + (size_t)(k * 64 + lane) * 4);
    }

    float av[16], bv[16];

    // ---- A: write g-order, read row-order
    #pragma unroll
    for (int k = 0; k < 4; ++k)
        *reinterpret_cast<vfloat4*>(&buf[(16 * k + wrow) * ROW_STRIDE + wq]) = pa[k];
    #pragma unroll
    for (int qq = 0; qq < 4; ++qq) {
        const vfloat4 t = *reinterpret_cast<const vfloat4*>(&buf[lane * ROW_STRIDE + qq * 4]);
        av[4 * qq + 0] = t.x; av[4 * qq + 1] = t.y;
        av[4 * qq + 2] = t.z; av[4 * qq + 3] = t.w;
    }

    // ---- B: same buffer (per-wave private; lgkmcnt deps order the reuse)
    #pragma unroll
    for (int k = 0; k < 4; ++k)
        *reinterpret_cast<vfloat4*>(&buf[(16 * k + wrow) * ROW_STRIDE + wq]) = pb[k];
    #pragma unroll
    for (int qq = 0; qq < 4; ++qq) {
        const vfloat4 t = *reinterpret_cast<const vfloat4*>(&buf[lane * ROW_STRIDE + qq * 4]);
        bv[4 * qq + 0] = t.x; bv[4 * qq + 1] = t.y;
        bv[4 * qq + 2] = t.z; bv[4 * qq + 3] = t.w;
    }

    // ---- 256-FMA geometric product, signs folded at compile time
    float acc[16];
    #pragma unroll
    for (int c = 0; c < 16; ++c) acc[c] = 0.0f;
    #pragma unroll
    for (int i = 0; i < 16; ++i) {
        #pragma unroll
        for (int j = 0; j < 16; ++j) {
            const int c = i ^ j;
            if (TAB.s[i][j] > 0) acc[c] = fmaf(av[i],  bv[j], acc[c]);
            else                 acc[c] = fmaf(av[i], -bv[j], acc[c]);
        }
    }

    // ---- out: write row-order, read g-order, store coalesced
    #pragma unroll
    for (int qq = 0; qq < 4; ++qq) {
        vfloat4 t;
        t.x = clip1000(acc[4 * qq + 0]);
        t.y = clip1000(acc[4 * qq + 1]);
        t.z = clip1000(acc[4 * qq + 2]);
        t.w = clip1000(acc[4 * qq + 3]);
        *reinterpret_cast<vfloat4*>(&buf[lane * ROW_STRIDE + qq * 4]) = t;
    }
    #pragma unroll
    for (int k = 0; k < 4; ++k) {
        const vfloat4 t = *reinterpret_cast<const vfloat4*>(&buf[(16 * k + wrow) * ROW_STRIDE + wq]);
        *reinterpret_cast<vfloat4*>(out + gbase + (size_t)(k * 64 + lane) * 4) = t;
    }
}

extern "C" void kernel_launch(void* const* d_in, const int* in_sizes, int n_in,
                              void* d_out, int out_size, void* d_ws, size_t ws_size,
                              hipStream_t stream) {
    const float* a = (const float*)d_in[0];
    const float* b = (const float*)d_in[1];
    float* out = (float*)d_out;

    const int nrows = in_sizes[0] / 16;               // N = 1048576
    const int block = 128;                            // 2 waves x 64 rows
    const int blocks = (nrows + 127) / 128;           // 8192

    clifford_gp_kernel<<<blocks, block, 0, stream>>>(a, b, out, nrows);
}